// Round 5
// baseline (432.064 us; speedup 1.0000x reference)
//
#include <hip/hip_runtime.h>

// CRF loss (B=1024, T=512, L=62, K=64) for MI355X / gfx950.
// One 64-lane wave per BATCH PAIR (512 blocks). Lane j = state j; the two
// batches' forward vectors are packed as float2 per state. Linear-domain
// recursion q_j <- W_j * sum_i q_i E_ij with E = exp(trans) duplicated into
// both float2 halves (E2[62], shared by the pair). Matvec: qsh (LDS, float2
// per state) read as 31x ds_read_b128 broadcast + 62 v_pk_fma_f32.
// Single wave per block -> no barriers (same-wave DS ops are in-order).
// Exact renorm every 2 steps per batch (c2 += log2(ssum_lane0), q *= rcp).
// Unified step loop to max(nmid); each batch's final alpha vector captured
// at its own m == nmid (log-domain finish with e_s). Gold fused; one
// atomicAdd of ln2*(zA+zB) - gold per block into pre-zeroed out[0].

#define SMALLF   (-1000.0f)
#define LOG2E_F  1.4426950408889634f
#define LN2_F    0.6931471805599453f

#if defined(__has_builtin)
#if __has_builtin(__builtin_amdgcn_exp2f)
#define EXP2F(x) __builtin_amdgcn_exp2f(x)
#else
#define EXP2F(x) exp2f(x)
#endif
#if __has_builtin(__builtin_amdgcn_logf)
#define LOG2F(x) __builtin_amdgcn_logf(x)
#else
#define LOG2F(x) log2f(x)
#endif
#if __has_builtin(__builtin_amdgcn_rcpf)
#define RCPF(x) __builtin_amdgcn_rcpf(x)
#else
#define RCPF(x) (1.0f / (x))
#endif
#else
#define EXP2F(x) exp2f(x)
#define LOG2F(x) log2f(x)
#define RCPF(x)  (1.0f / (x))
#endif

typedef float v2f __attribute__((ext_vector_type(2)));

__device__ __forceinline__ float bcast_first(float v) {
    return __uint_as_float(__builtin_amdgcn_readfirstlane(__float_as_uint(v)));
}

__global__ __launch_bounds__(64, 1) void crf_fused_kernel(
    const float* __restrict__ pred,     // (B,T,L)
    const int*   __restrict__ ref,      // (B,T)
    const int*   __restrict__ seq_len,  // (B,)
    const float* __restrict__ trans,    // (64,64)
    float*       __restrict__ out,      // scalar, pre-zeroed
    int T, int L)
{
    const int bp   = blockIdx.x;            // batch pair
    const int lane = threadIdx.x;
    const int sl0  = seq_len[2 * bp + 0];
    const int sl1  = seq_len[2 * bp + 1];
    const int n0   = sl0 - 1;               // middle-step count batch A
    const int n1   = sl1 - 1;               // middle-step count batch B
    const int mmax = (n0 > n1) ? n0 : n1;   // final step of batch c at m==n_c
    const float* pA = pred + (size_t)(2 * bp + 0) * T * L;
    const float* pB = pred + (size_t)(2 * bp + 1) * T * L;
    const int*   rA = ref  + (size_t)(2 * bp + 0) * T;
    const int*   rB = ref  + (size_t)(2 * bp + 1) * T;
    const bool mine = (lane < 62);

    __shared__ __align__(16) v2f qsh[64];

    // ---- gold score for both batches (accumulated into one register)
    float gacc = 0.f;
    {
        for (int t = lane; t < sl0; t += 64) {
            const int c = rA[t];
            gacc += pA[(size_t)t * L + c];
            if (t >= 1) gacc += trans[(rA[t - 1] << 6) + c];
        }
        for (int t = lane; t < sl1; t += 64) {
            const int c = rB[t];
            gacc += pB[(size_t)t * L + c];
            if (t >= 1) gacc += trans[(rB[t - 1] << 6) + c];
        }
        if (lane == 0)
            gacc += trans[(62 << 6) + rA[0]] + trans[(rA[sl0 - 1] << 6) + 63]
                  + trans[(62 << 6) + rB[0]] + trans[(rB[sl1 - 1] << 6) + 63];
    }

    // ---- E2[i] = exp(trans[i][lane]) duplicated in both halves (i < 62;
    // rows 62/63 are -10000 -> exactly 0, excluded from the matvec)
    v2f E2[62];
    float psum = 0.f;
#pragma unroll
    for (int i = 0; i < 62; ++i) {
        const float e = EXP2F(trans[i * 64 + lane] * LOG2E_F);
        E2[i].x = e; E2[i].y = e;
        psum += e;
    }

    // ---- init (t=1): q = exp2(pred row 0) * sum_i E_i; uniform SMALL -> c2
    v2f q;
    {
        const float oa = mine ? pA[lane] : 0.f;
        const float ob = mine ? pB[lane] : 0.f;
        q.x = psum * EXP2F(oa * LOG2E_F);
        q.y = psum * EXP2F(ob * LOG2E_F);
    }
    v2f c2; c2.x = SMALLF * LOG2E_F; c2.y = SMALLF * LOG2E_F;

    // ---- preload obs rows 1..8 (row for step m is m+1, clamped)
    float cA[8], cB[8];
#pragma unroll
    for (int u = 0; u < 8; ++u) {
        const int row = (1 + u < T) ? (1 + u) : (T - 1);
        cA[u] = mine ? pA[(size_t)row * L + lane] : 0.f;
        cB[u] = mine ? pB[(size_t)row * L + lane] : 0.f;
    }

    float alphaA = 0.f, alphaB = 0.f;

    for (int mb = 0; mb <= mmax; mb += 8) {
        // W for this chunk (off the serial chain)
        v2f Wv[8];
#pragma unroll
        for (int u = 0; u < 8; ++u) {
            Wv[u].x = EXP2F(cA[u] * LOG2E_F);
            Wv[u].y = EXP2F(cB[u] * LOG2E_F);
        }
        // prefetch next chunk's rows (mb+9 .. mb+16, clamped)
        float nA[8], nB[8];
#pragma unroll
        for (int u = 0; u < 8; ++u) {
            const int row = (mb + 9 + u < T) ? (mb + 9 + u) : (T - 1);
            nA[u] = mine ? pA[(size_t)row * L + lane] : 0.f;
            nB[u] = mine ? pB[(size_t)row * L + lane] : 0.f;
        }
#pragma unroll
        for (int u = 0; u < 8; ++u) {
            const int m = mb + u;
            if (m > mmax) break;

            qsh[lane] = q;                      // same-wave DS: in-order, no barrier
            v2f a0 = {0.f, 0.f}, a1 = {0.f, 0.f}, a2 = {0.f, 0.f}, a3 = {0.f, 0.f};
            const float4* q4 = (const float4*)qsh;
#pragma unroll
            for (int k = 0; k < 31; ++k) {      // states 2k, 2k+1 (0..61)
                const float4 v = q4[k];
                v2f qa; qa.x = v.x; qa.y = v.y;
                v2f qb; qb.x = v.z; qb.y = v.w;
                if (k & 1) {
                    a2 = __builtin_elementwise_fma(qa, E2[2 * k + 0], a2);
                    a3 = __builtin_elementwise_fma(qb, E2[2 * k + 1], a3);
                } else {
                    a0 = __builtin_elementwise_fma(qa, E2[2 * k + 0], a0);
                    a1 = __builtin_elementwise_fma(qb, E2[2 * k + 1], a1);
                }
            }
            const v2f ss = (a0 + a1) + (a2 + a3);

            if (m == n0) {                      // batch A final (log domain)
                const float pv = (sl0 < T) ? cA[u] : 0.f;   // row slen (or r_pad)
                const float ob = mine ? (pv + SMALLF)
                                      : ((lane == 62) ? SMALLF : 0.f);
                alphaA = c2.x + LOG2F(ss.x) + ob * LOG2E_F;
            }
            if (m == n1) {                      // batch B final
                const float pv = (sl1 < T) ? cB[u] : 0.f;
                const float ob = mine ? (pv + SMALLF)
                                      : ((lane == 62) ? SMALLF : 0.f);
                alphaB = c2.y + LOG2F(ss.y) + ob * LOG2E_F;
            }

            q = ss * Wv[u];
            if (m & 1) {                        // exact renorm every 2 steps
                const float ra = bcast_first(ss.x);
                const float rb = bcast_first(ss.y);
                c2.x += LOG2F(ra);
                c2.y += LOG2F(rb);
                v2f rr; rr.x = RCPF(ra); rr.y = RCPF(rb);
                q = q * rr;
            }
        }
#pragma unroll
        for (int u = 0; u < 8; ++u) { cA[u] = nA[u]; cB[u] = nB[u]; }
    }

    // ---- logsumexp over 64 states for each captured alpha
    float mxA = alphaA, mxB = alphaB;
#pragma unroll
    for (int k = 32; k >= 1; k >>= 1) {
        mxA = fmaxf(mxA, __shfl_xor(mxA, k, 64));
        mxB = fmaxf(mxB, __shfl_xor(mxB, k, 64));
    }
    float peA = EXP2F(alphaA - mxA);
    float peB = EXP2F(alphaB - mxB);
#pragma unroll
    for (int k = 32; k >= 1; k >>= 1) {
        peA += __shfl_xor(peA, k, 64);
        peB += __shfl_xor(peB, k, 64);
        gacc += __shfl_xor(gacc, k, 64);
    }

    if (lane == 0) {
        const float zA = mxA + LOG2F(peA);      // base-2 logZ, batch A
        const float zB = mxB + LOG2F(peB);      // base-2 logZ, batch B
        atomicAdd(out, LN2_F * (zA + zB) - gacc);
    }
}

extern "C" void kernel_launch(void* const* d_in, const int* in_sizes, int n_in,
                              void* d_out, int out_size, void* d_ws, size_t ws_size,
                              hipStream_t stream) {
    const float* pred  = (const float*)d_in[0];
    const int*   ref   = (const int*)  d_in[1];
    const int*   slen  = (const int*)  d_in[2];
    const float* trans = (const float*)d_in[3];

    const int B = in_sizes[2];                 // 1024
    const int T = in_sizes[1] / B;             // 512
    const int L = in_sizes[0] / in_sizes[1];   // 62

    hipMemsetAsync(d_out, 0, sizeof(float), stream);
    crf_fused_kernel<<<B / 2, 64, 0, stream>>>(pred, ref, slen, trans,
                                               (float*)d_out, T, L);
}

// Round 6
// 261.843 us; speedup vs baseline: 1.6501x; 1.6501x over previous
//
#include <hip/hip_runtime.h>

// CRF loss (B=1024, T=512, L=62, K=64) for MI355X / gfx950.
// One 64-lane wave per batch (lane j = state j), 1024 blocks (best makespan:
// runtime = straggler slen x per-step chain; R2/R5 showed sharing loses).
// Linear-domain recursion q_j <- W_j * sum_i q_i E_ij, E = exp(trans).
// Per-step chain, minimized for the DS pipe:
//   h (f16) -> ds_write_b16 -> 8x ds_read_b128 (broadcast, conflict-free)
//   -> 31x v_dot2_f32_f16 (f32 accumulate) -> exponent-only renorm
//   (integer bit-extract of ss_lane0's exponent; scale by exact 2^-(ex+6)
//   folded into the W multiply; integer scale accumulator off the chain).
// First step analytic (uniform SMALL -> c_base); final step in log domain.
// Gold path score fused; one atomicAdd(ln2*logZ2 - gold) per block.

#define SMALLF   (-1000.0f)
#define LOG2E_F  1.4426950408889634f
#define LN2_F    0.6931471805599453f

#if defined(__has_builtin)
#if __has_builtin(__builtin_amdgcn_exp2f)
#define EXP2F(x) __builtin_amdgcn_exp2f(x)
#else
#define EXP2F(x) exp2f(x)
#endif
#if __has_builtin(__builtin_amdgcn_logf)
#define LOG2F(x) __builtin_amdgcn_logf(x)
#else
#define LOG2F(x) log2f(x)
#endif
#else
#define EXP2F(x) exp2f(x)
#define LOG2F(x) log2f(x)
#endif

typedef _Float16 h2 __attribute__((ext_vector_type(2)));

#if defined(__has_builtin) && __has_builtin(__builtin_amdgcn_fdot2)
#define FDOT2(a, b, c) __builtin_amdgcn_fdot2((a), (b), (c), false)
#else
#define FDOT2(a, b, c) fmaf((float)(a).x, (float)(b).x, \
                            fmaf((float)(a).y, (float)(b).y, (c)))
#endif

__device__ __forceinline__ float bcast_first(float v) {
    return __uint_as_float(__builtin_amdgcn_readfirstlane(__float_as_uint(v)));
}

// ss[lane] = sum_{i<62} h_i * E[i][lane], h from LDS (f16), f32 accumulate.
// 8x float4 broadcast reads = 32 half2 pairs; pair 31 (rows 62/63) excluded.
__device__ __forceinline__ float dot62(const _Float16* __restrict__ hsh,
                                       const h2* __restrict__ Eh) {
    const float4* q4 = (const float4*)hsh;
    float a0 = 0.f, a1 = 0.f, a2 = 0.f, a3 = 0.f;
#pragma unroll
    for (int r = 0; r < 8; ++r) {
        const float4 v = q4[r];
        const h2 p0 = __builtin_bit_cast(h2, v.x);
        const h2 p1 = __builtin_bit_cast(h2, v.y);
        const h2 p2 = __builtin_bit_cast(h2, v.z);
        const h2 p3 = __builtin_bit_cast(h2, v.w);
        a0 = FDOT2(p0, Eh[4 * r + 0], a0);
        a1 = FDOT2(p1, Eh[4 * r + 1], a1);
        a2 = FDOT2(p2, Eh[4 * r + 2], a2);
        if (4 * r + 3 < 31)                      // skip pair 31 (rows 62/63)
            a3 = FDOT2(p3, Eh[4 * r + 3], a3);
    }
    return (a0 + a1) + (a2 + a3);
}

// wave-uniform scale 2^-(ex+6) from ss_lane0; accumulates ex+6 into Ci.
__device__ __forceinline__ float step_scale(float ss, int& Ci) {
    const float s0 = bcast_first(ss);
    const int ex = (int)((__float_as_uint(s0) >> 23) & 0xFF) - 127;  // s0>0 normal
    Ci += ex + 6;
    return __uint_as_float((unsigned)(127 - ex - 6) << 23);          // exact 2^-(ex+6)
}

__global__ __launch_bounds__(64, 1) void crf_fused_kernel(
    const float* __restrict__ pred,     // (B,T,L)
    const int*   __restrict__ ref,      // (B,T)
    const int*   __restrict__ seq_len,  // (B,)
    const float* __restrict__ trans,    // (64,64)
    float*       __restrict__ out,      // scalar, pre-zeroed
    int T, int L)
{
    const int b    = blockIdx.x;
    const int lane = threadIdx.x;
    const int slen = seq_len[b];
    const int nmid = slen - 1;              // middle steps t = 2..slen
    const float* prow = pred + (size_t)b * T * L;
    const int*   rrow = ref  + (size_t)b * T;
    const bool mine = (lane < 62);

    __shared__ __align__(16) _Float16 hsh[64];

    // ---- gold score, two-phase gather (indices first, then values)
    int cidx[8], pidx[8];
#pragma unroll
    for (int k = 0; k < 8; ++k) {
        const int t = lane + (k << 6);
        cidx[k] = (t < slen) ? rrow[t] : 0;
        pidx[k] = (t >= 1 && t < slen) ? rrow[t - 1] : 0;
    }
    float gacc = 0.f;
#pragma unroll
    for (int k = 0; k < 8; ++k) {
        const int t = lane + (k << 6);
        if (t < slen) {
            gacc += prow[(size_t)t * L + cidx[k]];
            if (t >= 1) gacc += trans[(pidx[k] << 6) + cidx[k]];
        }
    }
    if (lane == 0)
        gacc += trans[(62 << 6) + rrow[0]] + trans[(rrow[slen - 1] << 6) + 63];

    // ---- E rows 0..61 as half2 pairs (per lane j = column); rows 62/63 are 0
    h2 Eh[31];
    float psum = 0.f;
#pragma unroll
    for (int k = 0; k < 31; ++k) {
        const float e0 = EXP2F(trans[(2 * k + 0) * 64 + lane] * LOG2E_F);
        const float e1 = EXP2F(trans[(2 * k + 1) * 64 + lane] * LOG2E_F);
        Eh[k].x = (_Float16)e0; Eh[k].y = (_Float16)e1;
        psum += e0 + e1;
    }

    // ---- preload obs rows 1..8 (row for step m is m+1, clamped)
    float cur[8];
#pragma unroll
    for (int u = 0; u < 8; ++u) {
        const int row = (u + 1 < T) ? (u + 1) : (T - 1);
        cur[u] = mine ? prow[(size_t)row * L + lane] : 0.f;
    }

    // ---- init (t=1): q = exp2(pred0) * psum; uniform SMALL -> c_base
    int Ci = 0;                              // integer scale accumulator
    const float c_base = SMALLF * LOG2E_F;
    _Float16 hval;
    {
        const float q0 = psum * EXP2F((mine ? prow[lane] : 0.f) * LOG2E_F);
        const float sc = step_scale(q0, Ci);
        hval = (_Float16)(q0 * sc);
    }

    // ---- middle steps m = 0..nmid-1 in chunks of 8 (step m uses row m+1)
    const int nfull = nmid >> 3;
    const int rem   = nmid & 7;
    for (int c = 0; c < nfull; ++c) {
        float W[8], nxt[8];
#pragma unroll
        for (int u = 0; u < 8; ++u)
            W[u] = EXP2F(cur[u] * LOG2E_F);      // off the serial chain
        const int base = 8 * (c + 1) + 1;
#pragma unroll
        for (int u = 0; u < 8; ++u) {            // issue next chunk's loads
            const int row = (base + u < T) ? (base + u) : (T - 1);
            nxt[u] = mine ? prow[(size_t)row * L + lane] : 0.f;
        }
#pragma unroll
        for (int u = 0; u < 8; ++u) {
            hsh[lane] = hval;                    // same-wave DS: in-order
            const float ss = dot62(hsh, Eh);
            const float sc = step_scale(ss, Ci);
            hval = (_Float16)(ss * (W[u] * sc));
        }
#pragma unroll
        for (int u = 0; u < 8; ++u) cur[u] = nxt[u];
    }

    // ---- remainder middle steps: cur[u] holds row 8*nfull+1+u
#pragma unroll
    for (int u = 0; u < 7; ++u) {
        if (u < rem) {
            const float W = EXP2F(cur[u] * LOG2E_F);
            hsh[lane] = hval;
            const float ss = dot62(hsh, Eh);
            const float sc = step_scale(ss, Ci);
            hval = (_Float16)(ss * (W * sc));
        }
    }

    // ---- final step t = slen+1 in log domain (e_s has +1000)
    {
        hsh[lane] = hval;
        const float ssf = dot62(hsh, Eh);        // > 0 on all 64 lanes
        const float pvf = (slen < T) ? cur[rem] : 0.f;  // pred row slen (or r_pad)
        float ob;
        if (lane < 62)       ob = pvf + SMALLF;  // pred/r_pad + e_s SMALL
        else if (lane == 62) ob = SMALLF;        // SMALL + 0
        else                 ob = 0.f;           // SMALL + 1000
        const float alpha = c_base + (float)Ci + LOG2F(ssf) + ob * LOG2E_F;

        float mx = alpha;
#pragma unroll
        for (int k = 32; k >= 1; k >>= 1)
            mx = fmaxf(mx, __shfl_xor(mx, k, 64));
        float pe = EXP2F(alpha - mx);
#pragma unroll
        for (int k = 32; k >= 1; k >>= 1)
            pe += __shfl_xor(pe, k, 64);
#pragma unroll
        for (int k = 32; k >= 1; k >>= 1)
            gacc += __shfl_xor(gacc, k, 64);

        if (lane == 0) {
            const float logZ2 = mx + LOG2F(pe);  // base-2
            atomicAdd(out, LN2_F * logZ2 - gacc);
        }
    }
}

extern "C" void kernel_launch(void* const* d_in, const int* in_sizes, int n_in,
                              void* d_out, int out_size, void* d_ws, size_t ws_size,
                              hipStream_t stream) {
    const float* pred  = (const float*)d_in[0];
    const int*   ref   = (const int*)  d_in[1];
    const int*   slen  = (const int*)  d_in[2];
    const float* trans = (const float*)d_in[3];

    const int B = in_sizes[2];                 // 1024
    const int T = in_sizes[1] / B;             // 512
    const int L = in_sizes[0] / in_sizes[1];   // 62

    hipMemsetAsync(d_out, 0, sizeof(float), stream);
    crf_fused_kernel<<<B, 64, 0, stream>>>(pred, ref, slen, trans,
                                           (float*)d_out, T, L);
}